// Round 8
// baseline (124.882 us; speedup 1.0000x reference)
//
#include <hip/hip_runtime.h>

// BarrierNet fused MLP + CBF-QP filter — f16 MFMA, barrier-free, prepacked,
// 4-way tile ILP.
//
// Kernel 1 (prep): fp32 weights -> per-lane f16 MFMA B-fragments + bias
// tables in d_ws (~30 KB).
// Kernel 2 (main): each wave processes FOUR independent 16-row tiles in
// interleaved straight-line code. Weights (~104 regs) are shared across all
// chains; each chain adds only ~35 regs of activation state. R7 measured 2
// chains -> VALUBusy 56%; ~2 resident waves/SIMD x 4 chains = 8 concurrent
// dependency chains to hide MFMA/LDS/HBM latency. No __syncthreads: LDS
// tiles are wave-private, intra-wave DS ordering is in-order + lgkmcnt.
//
// XSTR=72 halfs (144 B): rows 16B-aligned for ds_read_b128; write/read bank
// patterns hit the structural 1KiB/8-cycle minimum (2-way overlaps only,
// free per m136). Keeps 4-slot-per-wave LDS at 40 KB/block.
//
// Spill ledger: (256,2) budget 256 regs; live ~= w 104 + a2 64 + a1 16 +
// biases 13 + misc ~25 = ~220. R5 showed an occupancy target above the live
// set -> 85 MB scratch traffic; WRITE_SIZE is the tripwire (should stay 4 MB).
//
// Layouts (HW-verified, learn_hip m89/m91/m120):
//   A-frag: lane holds A[m=lane&15][k=(lane>>4)*8 + j], j=0..7
//   B-frag: lane holds B[k=(lane>>4)*8+j][n=lane&15]  (= W[n][k], W:[out,in])
//   C/D   : lane holds D[row=(lane>>4)*4+reg][col=lane&15]

typedef _Float16 half8 __attribute__((ext_vector_type(8)));
typedef float floatx4 __attribute__((ext_vector_type(4)));

#define TPB   256
#define NW    4         // waves per block
#define NT    4         // tiles (chains) per wave
#define XSTR  72        // x-tile row stride in halfs (144 B, 16B-aligned)

// d_ws layout (bytes). Fragment region: half8[fragID][lane], fragID 0..7 =
// W1 n-tiles, 8..23 = W2 (nt2*4+kt), 24..25 = W3 heads.
#define WS_FRAG 0        // 26*64 half8  = 26624 B
#define WS_B1   26624    // 8*64 float   =  2048 B   b1f[nt][lane]
#define WS_B2   28672    // 4*64 float   =  1024 B   b2f[nt2][lane]
#define WS_B3   29696    // 64 float     =   256 B   b3v[lane]

__device__ __forceinline__ float fast_sigmoid(float z) {
    return __builtin_amdgcn_rcpf(1.0f + __expf(-z));
}

// ---------------- prep: fp32 weights -> f16 fragments in ws ----------------
__global__ __launch_bounds__(256) void prep_kernel(
    const float* __restrict__ W1,  const float* __restrict__ b1,
    const float* __restrict__ W21, const float* __restrict__ b21,
    const float* __restrict__ W22, const float* __restrict__ b22,
    const float* __restrict__ W31, const float* __restrict__ b31,
    const float* __restrict__ W32, const float* __restrict__ b32,
    unsigned char* __restrict__ ws)
{
    const int tid  = blockIdx.x * 256 + threadIdx.x;
    const int lane = tid & 63;
    const int m    = lane & 15;
    const int q    = lane >> 4;

    if (tid < 26 * 64) {
        const int f = tid >> 6;
        float v[8];
        if (f < 8) {                         // layer 1: W1 [128][10], K pad->32
            const float* wr = W1 + (f * 16 + m) * 10;
            #pragma unroll
            for (int j = 0; j < 8; ++j) {
                const int k = q * 8 + j;
                v[j] = (k < 10) ? wr[k] : 0.0f;
            }
        } else if (f < 24) {                 // layer 2: cat[W21;W22] [64][128]
            const int f2 = f - 8, nt2 = f2 >> 2, kt = f2 & 3;
            const int n2 = nt2 * 16 + m;
            const float* wr = (n2 < 32) ? (W21 + n2 * 128)
                                        : (W22 + (n2 - 32) * 128);
            #pragma unroll
            for (int j = 0; j < 8; ++j) v[j] = wr[kt * 32 + q * 8 + j];
        } else if (f == 24) {                // layer 3 kt=0: W31 rows, n=0,1
            #pragma unroll
            for (int j = 0; j < 8; ++j)
                v[j] = (m < 2) ? W31[m * 32 + q * 8 + j] : 0.0f;
        } else {                             // layer 3 kt=1: W32, n=2
            #pragma unroll
            for (int j = 0; j < 8; ++j)
                v[j] = (m == 2) ? W32[q * 8 + j] : 0.0f;
        }
        half8 h;
        #pragma unroll
        for (int j = 0; j < 8; ++j) h[j] = (_Float16)v[j];
        ((half8*)(ws + WS_FRAG))[tid] = h;
    }
    if (tid < 512)
        ((float*)(ws + WS_B1))[tid] = b1[(tid >> 6) * 16 + (tid & 15)];
    if (tid < 256) {
        const int n2 = (tid >> 6) * 16 + (tid & 15);
        ((float*)(ws + WS_B2))[tid] = (n2 < 32) ? b21[n2] : b22[n2 - 32];
    }
    if (tid < 64) {
        const int mm = tid & 15;
        ((float*)(ws + WS_B3))[tid] =
            (mm == 0) ? b31[0] : (mm == 1) ? b31[1] : (mm == 2) ? b32[0] : 0.0f;
    }
}

// ------------------------------- main -------------------------------------
__global__ __launch_bounds__(TPB, 2) void barriernet_kernel(
    const float* __restrict__ obs,
    const unsigned char* __restrict__ ws,
    float* __restrict__ out, int B)
{
    __shared__ _Float16 xs[NW * NT * 16 * XSTR];   // 36864 B
    __shared__ float    ep[NW * NT * 16 * 4];      //  4096 B

    const int tid  = threadIdx.x;
    const int wave = tid >> 6;
    const int lane = tid & 63;
    const int m    = lane & 15;
    const int q    = lane >> 4;

    // ---- weight fragments: 26 coalesced b128 loads + 13 bias loads ----
    const half8* wf = (const half8*)(ws + WS_FRAG);
    half8 w1f[8], w2f[16], w3f0, w3f1;
    #pragma unroll
    for (int nt = 0; nt < 8; ++nt)  w1f[nt] = wf[nt * 64 + lane];
    #pragma unroll
    for (int f2 = 0; f2 < 16; ++f2) w2f[f2] = wf[(8 + f2) * 64 + lane];
    w3f0 = wf[24 * 64 + lane];
    w3f1 = wf[25 * 64 + lane];

    const float* fB1 = (const float*)(ws + WS_B1);
    const float* fB2 = (const float*)(ws + WS_B2);
    float b1f[8], b2f[4];
    #pragma unroll
    for (int nt = 0; nt < 8; ++nt) b1f[nt] = fB1[nt * 64 + lane];
    #pragma unroll
    for (int nt2 = 0; nt2 < 4; ++nt2) b2f[nt2] = fB2[nt2 * 64 + lane];
    const float b3v = ((const float*)(ws + WS_B3))[lane];

    const int tiles = (B + 15) >> 4;
    const int tbase = (blockIdx.x * NW + wave) * NT;

    // Per-chain LDS bases (wave-private slots p=0..NT-1).
    _Float16*    xq[NT];
    const half8* xr[NT];
    float*       epw[NT];
    #pragma unroll
    for (int p = 0; p < NT; ++p) {
        _Float16* xw = xs + (wave * NT + p) * 16 * XSTR;
        xq[p]  = xw + q * 4 * XSTR + m;                 // write: +r*XSTR+nt*16
        xr[p]  = (const half8*)(xw + m * XSTR + q * 8); // read:  +kt*4 (half8)
        epw[p] = ep + (wave * NT + p) * 16 * 4;
    }

    // --- obs rows + A-fragments for all chains (loads issue back-to-back) ---
    const float* orow[NT];
    half8 a1[NT];
    int lrow0[NT];
    #pragma unroll
    for (int p = 0; p < NT; ++p) {
        int tile = tbase + p;
        if (tile >= tiles) tile = tiles - 1;            // dup work, benign
        int lr = (tile << 4) + m;
        if (lr >= B) lr = B - 1;
        lrow0[p] = lr;
        orow[p] = obs + (size_t)lr * 10;

        float g0=0,g1=0,g2=0,g3=0,g4=0,g5=0,g6=0,g7=0;
        if (q == 0) {
            float2 p0 = *(const float2*)(orow[p] + 0);
            float2 p1 = *(const float2*)(orow[p] + 2);
            float2 p2 = *(const float2*)(orow[p] + 4);
            float2 p3 = *(const float2*)(orow[p] + 6);
            g0=p0.x; g1=p0.y; g2=p1.x; g3=p1.y;
            g4=p2.x; g5=p2.y; g6=p3.x; g7=p3.y;
        } else if (q == 1) {
            float2 pp = *(const float2*)(orow[p] + 8);
            g0=pp.x; g1=pp.y;
        }
        a1[p][0]=(_Float16)g0; a1[p][1]=(_Float16)g1;
        a1[p][2]=(_Float16)g2; a1[p][3]=(_Float16)g3;
        a1[p][4]=(_Float16)g4; a1[p][5]=(_Float16)g5;
        a1[p][6]=(_Float16)g6; a1[p][7]=(_Float16)g7;
    }

    // --- layer 1: NTx8 independent MFMAs interleaved, silu, write x-tiles ---
    #pragma unroll
    for (int nt = 0; nt < 8; ++nt) {
        #pragma unroll
        for (int p = 0; p < NT; ++p) {
            floatx4 z = {b1f[nt], b1f[nt], b1f[nt], b1f[nt]};
            z = __builtin_amdgcn_mfma_f32_16x16x32_f16(a1[p], w1f[nt], z, 0, 0, 0);
            #pragma unroll
            for (int r = 0; r < 4; ++r) {
                float zz = z[r];
                xq[p][r * XSTR + nt * 16] = (_Float16)(zz * fast_sigmoid(zz));
            }
        }
    }

    // --- x-tiles -> layer-2 A-fragments ---
    half8 a2[NT][4];
    #pragma unroll
    for (int p = 0; p < NT; ++p)
        #pragma unroll
        for (int kt = 0; kt < 4; ++kt) a2[p][kt] = xr[p][kt * 4];

    // --- layer 2: 4 n-tiles x 4 k-tiles per chain, silu, write x2-tiles ---
    #pragma unroll
    for (int nt2 = 0; nt2 < 4; ++nt2) {
        #pragma unroll
        for (int p = 0; p < NT; ++p) {
            floatx4 z = {b2f[nt2], b2f[nt2], b2f[nt2], b2f[nt2]};
            #pragma unroll
            for (int kt = 0; kt < 4; ++kt)
                z = __builtin_amdgcn_mfma_f32_16x16x32_f16(a2[p][kt], w2f[nt2 * 4 + kt], z, 0, 0, 0);
            #pragma unroll
            for (int r = 0; r < 4; ++r) {
                float zz = z[r];
                xq[p][r * XSTR + nt2 * 16] = (_Float16)(zz * fast_sigmoid(zz));
            }
        }
    }

    // --- x2-tiles -> layer-3 A-fragments, heads ---
    #pragma unroll
    for (int p = 0; p < NT; ++p) {
        half8 a30 = xr[p][0];
        half8 a31 = xr[p][4];
        floatx4 d = {b3v, b3v, b3v, b3v};
        d = __builtin_amdgcn_mfma_f32_16x16x32_f16(a30, w3f0, d, 0, 0, 0);
        d = __builtin_amdgcn_mfma_f32_16x16x32_f16(a31, w3f1, d, 0, 0, 0);
        if (m < 3) {
            #pragma unroll
            for (int r = 0; r < 4; ++r)
                epw[p][(q * 4 + r) * 4 + m] = d[r];
        }
    }

    // --- fp32 CBF-QP epilogue: quad-0 lanes, one row per lane per chain ---
    #pragma unroll
    for (int p = 0; p < NT; ++p) {
        if (q == 0) {
            float4 e = ((const float4*)epw[p])[m];
            const float u0 = e.x, u1 = e.y, z32 = e.z;
            const float alpha = 4.0f * fast_sigmoid(z32);

            const float2 rxy = *(const float2*)(orow[p] + 6);
            const float2 vxy = *(const float2*)(orow[p] + 8);
            const float rx = rxy.x, ry = rxy.y, vx = vxy.x, vy = vxy.y;

            const float barrier = rx * rx + ry * ry - 0.64f;   // R_SAFE^2
            const float lf = -2.0f * (rx * vx + ry * vy);
            const float gx = -2.0f * rx, gy = -2.0f * ry;
            const float h  = lf + alpha * barrier;
            const float gg = gx * gx + gy * gy;
            const float viol = gx * u0 + gy * u1 - h;
            float lam = 0.0f;
            if (gg > 0.0f) lam = fmaxf(viol, 0.0f) / fmaxf(gg, 1e-12f);

            float2 r;
            r.x = fmaf(-lam, gx, u0);
            r.y = fmaf(-lam, gy, u1);
            *(float2*)(out + (size_t)lrow0[p] * 2) = r;
        }
    }
}

extern "C" void kernel_launch(void* const* d_in, const int* in_sizes, int n_in,
                              void* d_out, int out_size, void* d_ws, size_t ws_size,
                              hipStream_t stream) {
    const float* obs = (const float*)d_in[0];
    const float* W1  = (const float*)d_in[1];
    const float* b1  = (const float*)d_in[2];
    const float* W21 = (const float*)d_in[3];
    const float* b21 = (const float*)d_in[4];
    const float* W22 = (const float*)d_in[5];
    const float* b22 = (const float*)d_in[6];
    const float* W31 = (const float*)d_in[7];
    const float* b31 = (const float*)d_in[8];
    const float* W32 = (const float*)d_in[9];
    const float* b32 = (const float*)d_in[10];

    unsigned char* ws = (unsigned char*)d_ws;

    // prep: 26*64 fragment threads -> 7 blocks of 256
    prep_kernel<<<7, 256, 0, stream>>>(W1, b1, W21, b21, W22, b22,
                                       W31, b31, W32, b32, ws);

    const int B = in_sizes[0] / 10;                  // obs is [B,10]
    const int tiles = (B + 15) / 16;                 // 32768
    const int wavesN = (tiles + NT - 1) / NT;        // 8192
    const int grid  = (wavesN + NW - 1) / NW;        // 2048

    barriernet_kernel<<<grid, TPB, 0, stream>>>(obs, ws, (float*)d_out, B);
}